// Round 9
// baseline (111.679 us; speedup 1.0000x reference)
//
#include <hip/hip_runtime.h>
#include <hip/hip_bf16.h>
#include <stdint.h>
#include <stddef.h>

// NT-Xent loss, B=4096, D=256, N=8192, T=0.5.
// normalize(+zero sumexp) -> fused symmetric ZZ^T GEMM + exp row/col-sum +
// positive capture -> 1-block finalize/mean. No NxN materialization.
//
// R9: NO LDS AT ALL. R1-R8 evidence: the 2-barrier stage->LDS->MFMA cadence
// has a ~40 us latency floor insensitive to halving every volume (R8
// symmetry halved MFMA/LDS/L2/exp, gained only ~4 us; R7 counters: MfmaUtil
// 28% + VALUBusy 30% -> 40% of cycles idle). zn is 4 MB = L2-resident, and
// the B-fragment pattern from global is 16 rows x 64 B contiguous lines per
// wave-load -> read B fragments directly from L1/L2. Zero __syncthreads in
// the kernel; compiler pipelines next-iter loads freely; 8 waves/CU
// interleave without barrier convoys.
// Carry-overs: R8 symmetry (each unordered 128x128 tile-pair once: row-sums
// + col-sums via cross-quad shuffle + atomics), R7 __builtin_amdgcn_exp2f
// (single v_exp_f32), A-fragments register-resident full-D.
// Harness note: top-5 dispatches are the harness's 268 MB ws-poison fills
// (43.5 us, serialized) — dur_us floor ~58 us is outside kernel control.

#define B_ROWS 4096
#define D_DIM  256
#define N_ROWS 8192
#define BM 128
#define BN 64

typedef __bf16 bf16;
typedef bf16  bf16x8  __attribute__((ext_vector_type(8)));
typedef bf16  bf16x4  __attribute__((ext_vector_type(4)));
typedef float floatx4 __attribute__((ext_vector_type(4)));

// ---------------------------------------------------------------- normalize
// One wave per row: 256 fp32 -> L2-normalized bf16. Also zeroes sumexp[row].
__global__ __launch_bounds__(256) void normalize_kernel(
    const float* __restrict__ z_i, const float* __restrict__ z_j,
    bf16* __restrict__ zn, float* __restrict__ sumexp) {
  const int wave = threadIdx.x >> 6;
  const int lane = threadIdx.x & 63;
  const int row  = blockIdx.x * 4 + wave;
  const float* src = (row < B_ROWS) ? (z_i + (size_t)row * D_DIM)
                                    : (z_j + (size_t)(row - B_ROWS) * D_DIM);
  float4 v = ((const float4*)src)[lane];
  float ss = v.x * v.x + v.y * v.y + v.z * v.z + v.w * v.w;
  #pragma unroll
  for (int m = 1; m < 64; m <<= 1) ss += __shfl_xor(ss, m);
  const float rn = rsqrtf(ss);
  bf16x4 o;
  o[0] = (bf16)(v.x * rn);
  o[1] = (bf16)(v.y * rn);
  o[2] = (bf16)(v.z * rn);
  o[3] = (bf16)(v.w * rn);
  ((bf16x4*)(zn + (size_t)row * D_DIM))[lane] = o;
  if (lane == 0) sumexp[row] = 0.f;
}

// ------------------------------------------------------- fused sim+exp+sum
// Grid: 64 ri x 8 cj = 512 blocks. Block (ri,cj): tile-pairs s = 4cj+p,
// p=0..3 (+s=32 when cj==7 && ri<32); each pair = two 64-col sub-tiles ->
// 8 or 10 iterations. 4 waves in 2x2; wave = 64 rows x 32 cols = 4x2 frags
// of 16x16x32 bf16 MFMA, full-D accumulate. B fragments loaded straight
// from global (L1/L2): per (kq,tj) a wave reads 16 rows x 64 B contiguous.
__global__ __launch_bounds__(256, 2) void simexp_kernel(
    const bf16* __restrict__ zn, float* __restrict__ sumexp,
    float* __restrict__ pos) {
  const int tid   = threadIdx.x;
  const int wave  = tid >> 6;
  const int lane  = tid & 63;
  const int lcol  = lane & 15;   // MFMA: A row / B col / C col
  const int lquad = lane >> 4;   // MFMA: k-group / C row-group
  const int wr = (wave >> 1) * 64;  // wave row offset in 128
  const int wc = (wave & 1) * 32;   // wave col offset in 64
  const int ri = blockIdx.x >> 3;   // row tile 0..63
  const int cj = blockIdx.x & 7;    // s-chunk 0..7
  const int row_base = ri * BM;
  const int niter = (cj == 7 && ri < 32) ? 10 : 8;

  // j64-tile index for iteration it: pair p = it>>1, ct = (ri+4cj+p) & 63
  auto jt64 = [&](int it) {
    return 2 * ((ri + 4 * cj + (it >> 1)) & 63) + (it & 1);
  };

  // A fragments, register-resident for the whole block.
  // af[ti][kq]: row = row_base+wr+ti*16+lcol, k = kq*32 + lquad*8 .. +7
  floatx4 af[4][8];
  #pragma unroll
  for (int ti = 0; ti < 4; ++ti) {
    const bf16* arow =
        zn + (size_t)(row_base + wr + ti * 16 + lcol) * D_DIM + lquad * 8;
    #pragma unroll
    for (int kq = 0; kq < 8; ++kq)
      af[ti][kq] = *(const floatx4*)(arow + kq * 32);
  }

  float rowsum[4][4];  // [ti][r]; row = wr + ti*16 + lquad*4 + r
  #pragma unroll
  for (int ti = 0; ti < 4; ++ti)
    #pragma unroll
    for (int r = 0; r < 4; ++r) rowsum[ti][r] = 0.f;

  // per-lane B base offset (within a j64-tile): row = wc+tj*16+lcol,
  // element offset = row*256 + lquad*8 ; per kq add 32 elements (64 B imm)
  const int boff0 = (wc + 0 * 16 + lcol) * D_DIM + lquad * 8;
  const int boff1 = (wc + 1 * 16 + lcol) * D_DIM + lquad * 8;

  #pragma unroll 1  // keep body small (I$); niter is dynamic anyway
  for (int t = 0; t < niter; ++t) {
    const int jt = jt64(t);
    const bf16* bbase = zn + (size_t)jt * BN * D_DIM;

    floatx4 acc[4][2];
    #pragma unroll
    for (int ti = 0; ti < 4; ++ti)
      #pragma unroll
      for (int tj = 0; tj < 2; ++tj) acc[ti][tj] = floatx4{0.f, 0.f, 0.f, 0.f};

    #pragma unroll
    for (int kq = 0; kq < 8; ++kq) {
      bf16x8 bfr[2];
      bfr[0] = *(const bf16x8*)(bbase + boff0 + kq * 32);
      bfr[1] = *(const bf16x8*)(bbase + boff1 + kq * 32);
      #pragma unroll
      for (int ti = 0; ti < 4; ++ti)
        #pragma unroll
        for (int tj = 0; tj < 2; ++tj)
          acc[ti][tj] = __builtin_amdgcn_mfma_f32_16x16x32_bf16(
              __builtin_bit_cast(bf16x8, af[ti][kq]), bfr[tj], acc[ti][tj],
              0, 0, 0);
    }

    // epilogue: e = exp(sim/T) = exp(2*dot) = 2^(v * 2/ln2)
    const int s    = 4 * cj + (t >> 1);
    const bool diag = (s == 0);
    const bool posT = (s == 32);
    const int col_base = jt * BN;
    float colsum[2] = {0.f, 0.f};
    #pragma unroll
    for (int ti = 0; ti < 4; ++ti) {
      #pragma unroll
      for (int tj = 0; tj < 2; ++tj) {
        #pragma unroll
        for (int r = 0; r < 4; ++r) {
          const float v = acc[ti][tj][r];
          float e = __builtin_amdgcn_exp2f(v * 2.8853900817779268f);
          if (diag || posT) {
            const int rg = row_base + wr + ti * 16 + lquad * 4 + r;
            const int cg = col_base + wc + tj * 16 + lcol;
            if (diag && cg == rg) e = 0.f;               // mask self
            if (posT && cg == rg + B_ROWS) {             // positive pair
              pos[rg] = 2.0f * v;
              pos[cg] = 2.0f * v;
            }
          }
          rowsum[ti][r] += e;
          colsum[tj]    += e;
        }
      }
    }

    // symmetric contribution: col-sums -> rows of the partner tile.
    // (skip on diag tile: both orientations already inside the tile)
    if (!diag) {
      #pragma unroll
      for (int tj = 0; tj < 2; ++tj) {
        float cs = colsum[tj];
        cs += __shfl_xor(cs, 16);
        cs += __shfl_xor(cs, 32);
        if (lquad == 0)
          atomicAdd(&sumexp[col_base + wc + tj * 16 + lcol], cs);
      }
    }
  }

  // reduce the 16 col-lanes of rowsum, then 1 atomic per row per wave
  #pragma unroll
  for (int ti = 0; ti < 4; ++ti) {
    #pragma unroll
    for (int r = 0; r < 4; ++r) {
      float s2 = rowsum[ti][r];
      s2 += __shfl_xor(s2, 1);
      s2 += __shfl_xor(s2, 2);
      s2 += __shfl_xor(s2, 4);
      s2 += __shfl_xor(s2, 8);
      if (lcol == 0) {
        const int grow = row_base + wr + ti * 16 + lquad * 4 + r;
        atomicAdd(&sumexp[grow], s2);
      }
    }
  }
}

// ------------------------------------------------- finalize + mean (1 block)
// loss_i = log(sumexp_i) - pos_i ; out = mean(loss)
__global__ __launch_bounds__(1024) void reduce_kernel(
    const float* __restrict__ sumexp, const float* __restrict__ pos,
    float* __restrict__ out) {
  __shared__ float ws[16];
  const int tid = threadIdx.x;
  float s = 0.f;
  const float ln2 = 0.6931471805599453f;
  for (int k = tid; k < N_ROWS; k += 1024)
    s += __builtin_amdgcn_logf(sumexp[k]) * ln2 - pos[k];
  #pragma unroll
  for (int m = 1; m < 64; m <<= 1) s += __shfl_xor(s, m);
  const int wave = tid >> 6, lane = tid & 63;
  if (lane == 0) ws[wave] = s;
  __syncthreads();
  if (wave == 0) {
    float t = (lane < 16) ? ws[lane] : 0.f;
    #pragma unroll
    for (int m = 1; m < 16; m <<= 1) t += __shfl_xor(t, m);
    if (lane == 0) out[0] = t * (1.0f / N_ROWS);
  }
}

extern "C" void kernel_launch(void* const* d_in, const int* in_sizes, int n_in,
                              void* d_out, int out_size, void* d_ws,
                              size_t ws_size, hipStream_t stream) {
  const float* z_i = (const float*)d_in[0];
  const float* z_j = (const float*)d_in[1];
  float* out = (float*)d_out;

  // workspace layout: zn (4 MB bf16) | sumexp (32 KB) | pos (32 KB)
  bf16* zn = (bf16*)d_ws;
  float* sumexp = (float*)((char*)d_ws + (size_t)N_ROWS * D_DIM * sizeof(bf16));
  float* pos = sumexp + N_ROWS;

  normalize_kernel<<<N_ROWS / 4, 256, 0, stream>>>(z_i, z_j, zn, sumexp);
  simexp_kernel<<<512, 256, 0, stream>>>(zn, sumexp, pos);
  reduce_kernel<<<1, 1024, 0, stream>>>(sumexp, pos, out);
}

// Round 10
// 107.116 us; speedup vs baseline: 1.0426x; 1.0426x over previous
//
#include <hip/hip_runtime.h>
#include <hip/hip_bf16.h>
#include <stdint.h>
#include <stddef.h>

// NT-Xent loss, B=4096, D=256, N=8192, T=0.5.
// normalize(+zero sumexp) -> fused symmetric ZZ^T GEMM + exp row/col-sum +
// positive capture -> 1-block finalize/mean. No NxN materialization.
//
// R10: OCCUPANCY-FIRST. R1-R9 all ran 2 waves/SIMD (A-register-resident
// design needs ~220 regs/wave; m69: waves/SIMD halve at 128/256) and were
// latency-bound at ~17% occupancy regardless of staging structure. Now:
// BM=64 A-tile (32 KB) in LDS, staged ONCE per block (single barrier),
// shared by all 4 waves -> ~100 regs/wave -> 4 waves/SIMD, 4 blocks/CU,
// 16 waves/CU. B-fragments read directly from L2 (64 B lines); the loop
// body has ZERO barriers. Symmetry at 64-granularity: each unordered
// tile-pair once (row-sums + cross-quad col-sums), s=64 tiles carry the
// positive pairs. Carry-overs: __builtin_amdgcn_exp2f (single v_exp_f32),
// XOR-swizzled LDS (quarter-wave 2-way = free, m136).
// Harness note: ~58 us of dur_us is fixed overhead (268 MB ws re-poison
// fill at 43.5 us + restores) outside kernel control.

#define B_ROWS 4096
#define D_DIM  256
#define N_ROWS 8192
#define BM 64

typedef __bf16 bf16;
typedef bf16  bf16x8  __attribute__((ext_vector_type(8)));
typedef bf16  bf16x4  __attribute__((ext_vector_type(4)));
typedef float floatx4 __attribute__((ext_vector_type(4)));

// ---------------------------------------------------------------- normalize
// One wave per row: 256 fp32 -> L2-normalized bf16. Also zeroes sumexp[row].
__global__ __launch_bounds__(256) void normalize_kernel(
    const float* __restrict__ z_i, const float* __restrict__ z_j,
    bf16* __restrict__ zn, float* __restrict__ sumexp) {
  const int wave = threadIdx.x >> 6;
  const int lane = threadIdx.x & 63;
  const int row  = blockIdx.x * 4 + wave;
  const float* src = (row < B_ROWS) ? (z_i + (size_t)row * D_DIM)
                                    : (z_j + (size_t)(row - B_ROWS) * D_DIM);
  float4 v = ((const float4*)src)[lane];
  float ss = v.x * v.x + v.y * v.y + v.z * v.z + v.w * v.w;
  #pragma unroll
  for (int m = 1; m < 64; m <<= 1) ss += __shfl_xor(ss, m);
  const float rn = rsqrtf(ss);
  bf16x4 o;
  o[0] = (bf16)(v.x * rn);
  o[1] = (bf16)(v.y * rn);
  o[2] = (bf16)(v.z * rn);
  o[3] = (bf16)(v.w * rn);
  ((bf16x4*)(zn + (size_t)row * D_DIM))[lane] = o;
  if (lane == 0) sumexp[row] = 0.f;
}

// ------------------------------------------------------- fused sim+exp+sum
// Grid: 128 ri x 8 cj = 1024 blocks (4/CU). Block (ri,cj): pairs s=8cj+p,
// p=0..7, two pairs per iteration (4 iters x 128 cols); block cj==7,ri<64
// also handles s=64 (positive tiles) as a 5th iteration on waves 0,1.
// 4 waves: wave w covers all 64 rows x 32 cols; pair index = w>>1, col
// slice = (w&1)*32. acc[4][2] frags of 16x16x32 bf16 MFMA, full-D.
// A-frags from LDS (XOR-swizzled: 16B chunk kc of row n at slot
// (kc&24)|((kc&7)^(n&7)); quarter-wave = fixed lquad -> 8 chunks x 2 lanes
// = 32 banks 2-way = conflict-free). B-frags from global: 16 x 64 B lines
// per wave-load, L2-resident zn.
__global__ __launch_bounds__(256, 4) void simexp_kernel(
    const bf16* __restrict__ zn, float* __restrict__ sumexp,
    float* __restrict__ pos) {
  __shared__ __align__(16) bf16 As[BM * D_DIM];  // 32 KB

  const int tid   = threadIdx.x;
  const int wave  = tid >> 6;
  const int lane  = tid & 63;
  const int lcol  = lane & 15;   // MFMA: A/B input row-col index
  const int lquad = lane >> 4;   // MFMA: k-group / C row-group
  const int ri = blockIdx.x >> 3;   // row tile 0..127 (64-row granularity)
  const int cj = blockIdx.x & 7;    // s-chunk 0..7
  const int row_base = ri * BM;
  const bool tail_block = (cj == 7 && ri < 64);
  const int niter = tail_block ? 5 : 4;

  // stage A-tile once (8 x global_load_lds width-16 per thread)
  {
    const bf16* asrc = zn + (size_t)row_base * D_DIM;
    #pragma unroll
    for (int it = 0; it < 8; ++it) {
      const int s   = it * 256 + tid;   // chunk slot 0..2047
      const int n   = s >> 5;           // row-in-tile 0..63
      const int kcs = s & 31;           // swizzled slot
      const int kc  = (kcs & 24) | ((kcs & 7) ^ (n & 7));
      __builtin_amdgcn_global_load_lds(
          (const __attribute__((address_space(1))) unsigned int*)
              (asrc + (size_t)n * D_DIM + kc * 8),
          (__attribute__((address_space(3))) unsigned int*)&As[s * 8],
          16, 0, 0);
    }
  }

  float rowsum[4][4];  // [ti][r]; row-in-tile = ti*16 + lquad*4 + r
  #pragma unroll
  for (int ti = 0; ti < 4; ++ti)
    #pragma unroll
    for (int r = 0; r < 4; ++r) rowsum[ti][r] = 0.f;

  // per-lane B element offsets within a 64-col tile (constant across iters)
  const int slice_col = (wave & 1) * 32;
  const int boff0 = (slice_col + lcol) * D_DIM + lquad * 8;        // tj=0
  const int boff1 = (slice_col + 16 + lcol) * D_DIM + lquad * 8;   // tj=1

  __syncthreads();  // the ONLY barrier: A staged & visible

  #pragma unroll 1
  for (int q = 0; q < niter; ++q) {
    const bool tail = (q == 4);
    if (tail && wave >= 2) break;  // tail pair served by waves 0,1 only
    const int ct = tail ? (ri + 64)
                        : ((ri + 8 * cj + 2 * q + (wave >> 1)) & 127);
    const bf16* bbase = zn + (size_t)ct * BM * D_DIM;

    floatx4 acc[4][2];
    #pragma unroll
    for (int ti = 0; ti < 4; ++ti)
      #pragma unroll
      for (int tj = 0; tj < 2; ++tj) acc[ti][tj] = floatx4{0.f, 0.f, 0.f, 0.f};

    #pragma unroll
    for (int kq = 0; kq < 8; ++kq) {
      const int kc   = kq * 4 + lquad;
      const int slot = (kc & 24) | ((kc & 7) ^ (lcol & 7));
      const bf16x8 b0 = *(const bf16x8*)(bbase + boff0 + kq * 32);
      const bf16x8 b1 = *(const bf16x8*)(bbase + boff1 + kq * 32);
      #pragma unroll
      for (int ti = 0; ti < 4; ++ti) {
        const bf16x8 a =
            *(const bf16x8*)&As[(ti * 16 + lcol) * D_DIM + slot * 8];
        acc[ti][0] = __builtin_amdgcn_mfma_f32_16x16x32_bf16(a, b0, acc[ti][0],
                                                             0, 0, 0);
        acc[ti][1] = __builtin_amdgcn_mfma_f32_16x16x32_bf16(a, b1, acc[ti][1],
                                                             0, 0, 0);
      }
    }

    // epilogue: e = exp(sim/T) = exp(2*dot) = 2^(v * 2/ln2)
    const bool diagw = (cj == 0 && q == 0 && wave < 2);  // ct == ri tile
    const int col_base = ct * BM + slice_col;
    float colsum[2] = {0.f, 0.f};
    #pragma unroll
    for (int ti = 0; ti < 4; ++ti) {
      #pragma unroll
      for (int tj = 0; tj < 2; ++tj) {
        #pragma unroll
        for (int r = 0; r < 4; ++r) {
          const float v = acc[ti][tj][r];
          float e = __builtin_amdgcn_exp2f(v * 2.8853900817779268f);
          if (diagw || tail) {
            const int rg = row_base + ti * 16 + lquad * 4 + r;
            const int cg = col_base + tj * 16 + lcol;
            if (diagw && cg == rg) e = 0.f;              // mask self
            if (tail && cg == rg + B_ROWS) {             // positive pair
              pos[rg] = 2.0f * v;
              pos[cg] = 2.0f * v;
            }
          }
          rowsum[ti][r] += e;
          colsum[tj]    += e;
        }
      }
    }

    // symmetric contribution: col-sums -> rows(ct). Skip on the self-diag
    // tile (its row-sums already cover both orientations).
    if (!diagw) {
      #pragma unroll
      for (int tj = 0; tj < 2; ++tj) {
        float cs = colsum[tj];
        cs += __shfl_xor(cs, 16);
        cs += __shfl_xor(cs, 32);
        if (lquad == 0)
          atomicAdd(&sumexp[col_base + tj * 16 + lcol], cs);
      }
    }
  }

  // reduce the 16 col-lanes of rowsum, then 1 atomic per row per wave
  #pragma unroll
  for (int ti = 0; ti < 4; ++ti) {
    #pragma unroll
    for (int r = 0; r < 4; ++r) {
      float s2 = rowsum[ti][r];
      s2 += __shfl_xor(s2, 1);
      s2 += __shfl_xor(s2, 2);
      s2 += __shfl_xor(s2, 4);
      s2 += __shfl_xor(s2, 8);
      if (lcol == 0) {
        const int grow = row_base + ti * 16 + lquad * 4 + r;
        atomicAdd(&sumexp[grow], s2);
      }
    }
  }
}

// ------------------------------------------------- finalize + mean (1 block)
// loss_i = log(sumexp_i) - pos_i ; out = mean(loss)
__global__ __launch_bounds__(1024) void reduce_kernel(
    const float* __restrict__ sumexp, const float* __restrict__ pos,
    float* __restrict__ out) {
  __shared__ float ws[16];
  const int tid = threadIdx.x;
  float s = 0.f;
  const float ln2 = 0.6931471805599453f;
  for (int k = tid; k < N_ROWS; k += 1024)
    s += __builtin_amdgcn_logf(sumexp[k]) * ln2 - pos[k];
  #pragma unroll
  for (int m = 1; m < 64; m <<= 1) s += __shfl_xor(s, m);
  const int wave = tid >> 6, lane = tid & 63;
  if (lane == 0) ws[wave] = s;
  __syncthreads();
  if (wave == 0) {
    float t = (lane < 16) ? ws[lane] : 0.f;
    #pragma unroll
    for (int m = 1; m < 16; m <<= 1) t += __shfl_xor(t, m);
    if (lane == 0) out[0] = t * (1.0f / N_ROWS);
  }
}

extern "C" void kernel_launch(void* const* d_in, const int* in_sizes, int n_in,
                              void* d_out, int out_size, void* d_ws,
                              size_t ws_size, hipStream_t stream) {
  const float* z_i = (const float*)d_in[0];
  const float* z_j = (const float*)d_in[1];
  float* out = (float*)d_out;

  // workspace layout: zn (4 MB bf16) | sumexp (32 KB) | pos (32 KB)
  bf16* zn = (bf16*)d_ws;
  float* sumexp = (float*)((char*)d_ws + (size_t)N_ROWS * D_DIM * sizeof(bf16));
  float* pos = sumexp + N_ROWS;

  normalize_kernel<<<N_ROWS / 4, 256, 0, stream>>>(z_i, z_j, zn, sumexp);
  simexp_kernel<<<1024, 256, 0, stream>>>(zn, sumexp, pos);
  reduce_kernel<<<1, 1024, 0, stream>>>(sumexp, pos, out);
}